// Round 5
// baseline (113.814 us; speedup 1.0000x reference)
//
#include <hip/hip_runtime.h>
#include <hip/hip_bf16.h>
#include <stdint.h>

#define M_DIM 8192
#define N_DIM 1024
#define K_DIM 4096

typedef __bf16 bf16x8 __attribute__((ext_vector_type(8)));
typedef float f32x4 __attribute__((ext_vector_type(4)));
typedef __hip_bfloat16 bf16_t;

__device__ __forceinline__ void gload_lds16(const void* g, void* l) {
  __builtin_amdgcn_global_load_lds(
      (const __attribute__((address_space(1))) void*)g,
      (__attribute__((address_space(3))) void*)l, 16, 0, 0);
}

// ---- pack W only: fp32 [1024][4096] -> bf16 tiled [rt][kt][256 rows][8 chunks]
// with st-swizzle pre-applied (chunk' = chunk ^ (row&7)).
__global__ __launch_bounds__(256) void pack_w(const float* __restrict__ W,
                                              int4* __restrict__ pB) {
  const unsigned t = blockIdx.x * 256 + threadIdx.x;   // < 524288
  const unsigned cp = t & 7;
  const unsigned tmp = t >> 3;
  const unsigned r = tmp & 255;
  const unsigned tmp2 = tmp >> 8;
  const unsigned kt = tmp2 & 63;
  const unsigned rt = tmp2 >> 6;
  const unsigned srow = (rt << 8) + r;
  const unsigned k0 = (kt << 6) + ((cp ^ (r & 7)) << 3);
  const float4* s = (const float4*)(W + (size_t)srow * 4096 + k0);
  float4 a = s[0], b = s[1];
  union { bf16_t h[8]; int4 v; } u;
  u.h[0] = __float2bfloat16(a.x); u.h[1] = __float2bfloat16(a.y);
  u.h[2] = __float2bfloat16(a.z); u.h[3] = __float2bfloat16(a.w);
  u.h[4] = __float2bfloat16(b.x); u.h[5] = __float2bfloat16(b.y);
  u.h[6] = __float2bfloat16(b.z); u.h[7] = __float2bfloat16(b.w);
  pB[t] = u.v;
}

// ---- 8-phase 256x256 GEMM, A reg-staged from raw fp32, DEEP prefetch ---------
// 512 thr = 8 waves (2M x 4N), per-wave C = 128x64, snake residency.
// A loads issued 3 phases before their cvt_write (vs 1 in r4): gb(Ah1(g+2))
// at P1(g) -> written P0-tail(g+1); ga(Ah0(g+3)) at P3(g) -> written
// P2-tail(g+1). FIFO vmcnt ledger (issue order), steady state:
//   entry(g):  [ga4(Ah0(g+2)), B2(Bh1(g+1))]
//   P1 issues  gb4(Ah1(g+2)), B2(Bh0(g+1))          -> 12 outstanding
//   P2-tail    vmcnt(8) retires ga4 -> cvt_write Ah0(g+2)
//   P3 issues  ga4(Ah0(g+3)), B2(Bh1(g+2))          -> 14 outstanding
//   P3-end     vmcnt(6) retires Bh1(g+1), gb4, Bh0(g+1) -> invariant restored
//   P0-tail    NO wait (gb retired at P3-end) -> cvt_write Ah1(g+1)
// Visibility: every cvt_write is lgkm-drained at the writer's next lgkmcnt(0)
// and >=2 barriers precede its first reader; every staged slot is vm-retired
// by a counted vmcnt + barrier before its readers.
__device__ __forceinline__ void stage_half(const char* g, char* smem, int ldsoff, int tid) {
  gload_lds16(g + tid * 16, smem + ldsoff + tid * 16);
  gload_lds16(g + 8192 + tid * 16, smem + ldsoff + 8192 + tid * 16);
}

__device__ __forceinline__ void issue4(const float* g, float4* r) {
  const float4* s = (const float4*)g;
  r[0] = s[0]; r[1] = s[1]; r[2] = s[2]; r[3] = s[3];
}

__device__ __forceinline__ void cvt_write(const float4* r, char* base, int o0) {
  union { bf16_t h[8]; int4 v; } u0, u1;
  u0.h[0] = __float2bfloat16(r[0].x); u0.h[1] = __float2bfloat16(r[0].y);
  u0.h[2] = __float2bfloat16(r[0].z); u0.h[3] = __float2bfloat16(r[0].w);
  u0.h[4] = __float2bfloat16(r[1].x); u0.h[5] = __float2bfloat16(r[1].y);
  u0.h[6] = __float2bfloat16(r[1].z); u0.h[7] = __float2bfloat16(r[1].w);
  u1.h[0] = __float2bfloat16(r[2].x); u1.h[1] = __float2bfloat16(r[2].y);
  u1.h[2] = __float2bfloat16(r[2].z); u1.h[3] = __float2bfloat16(r[2].w);
  u1.h[4] = __float2bfloat16(r[3].x); u1.h[5] = __float2bfloat16(r[3].y);
  u1.h[6] = __float2bfloat16(r[3].z); u1.h[7] = __float2bfloat16(r[3].w);
  *(int4*)(base + o0) = u0.v;
  *(int4*)(base + (o0 ^ 16)) = u1.v;
}

__global__ __launch_bounds__(512, 2) void gemm8(
    const float* __restrict__ Araw, const char* __restrict__ pB,
    float* __restrict__ V0, float* __restrict__ V1p, int NT) {
  extern __shared__ char smem[];
  const int tid = threadIdx.x;
  const int lane = tid & 63, wave = tid >> 6;
  const int wm = wave >> 2, wn = wave & 3;
  const int lrow = lane & 15, lkc = lane >> 4;

  const int cpx = (int)gridDim.x >> 3;
  const int swz = ((int)blockIdx.x & 7) * cpx + ((int)blockIdx.x >> 3);
  const int split = swz >> 7;
  const int rem = swz & 127;
  const int mt = rem >> 2, nt = rem & 3;

  const char* Bbase = pB + ((size_t)nt * 64 + (size_t)split * NT) * 32768;
  float* V = split ? V1p : V0;

  // A global source: thread handles row (tid>>2) of the 128-row half,
  // 16 floats starting at col (tid&3)*16 of the 64-col K-step.
  const float* aG = Araw + (size_t)(mt * 256 + (tid >> 2)) * K_DIM +
                    (size_t)split * (NT * 64) + (tid & 3) * 16;
  // Swizzled LDS write offset within a half-slot (2-way bank alias = free).
  const int wrO0 = (tid >> 2) * 128 + ((((tid & 3) << 1) ^ ((tid >> 2) & 7)) << 4);

  int colw[2];
  colw[0] = ((lkc) ^ (lrow & 7)) << 4;
  colw[1] = ((4 + lkc) ^ (lrow & 7)) << 4;
  int aRow[4], bRow[2];
  #pragma unroll
  for (int f = 0; f < 4; ++f) aRow[f] = (wm * 64 + f * 16 + lrow) * 128;
  #pragma unroll
  for (int f2 = 0; f2 < 2; ++f2) bRow[f2] = 32768 + (wn * 32 + f2 * 16 + lrow) * 128;

  f32x4 acc[2][4][2][2];
  #pragma unroll
  for (int a0 = 0; a0 < 2; ++a0)
    #pragma unroll
    for (int a1 = 0; a1 < 4; ++a1)
      #pragma unroll
      for (int a2 = 0; a2 < 2; ++a2)
        #pragma unroll
        for (int a3 = 0; a3 < 2; ++a3)
          acc[a0][a1][a2][a3] = (f32x4){0.f, 0.f, 0.f, 0.f};

  const int ktm = NT - 1;
  float4 ga[4], gb[4];

  // ---- Prologue: build tile0 + Ah0(1) in LDS; end with outstanding
  // [ga4(Ah0(2)), B2(Bh1(1))] and gb holding Ah1(1) data (retired).
  issue4(aG, ga);                                          // ga=Ah0(0) [4]
  issue4(aG + 128 * K_DIM, gb);                            // gb=Ah1(0) [4]
  stage_half(Bbase, smem, 32768, tid);                     // Bh0(0)    [2]
  stage_half(Bbase + 16384, smem, 32768 + 16384, tid);     // Bh1(0)    [2]
  asm volatile("s_waitcnt vmcnt(8)" ::: "memory");         // ga done
  cvt_write(ga, smem + 0, wrO0);                           // Ah0(0)
  asm volatile("s_waitcnt vmcnt(4)" ::: "memory");         // gb done
  cvt_write(gb, smem + 16384, wrO0);                       // Ah1(0)
  issue4(aG + 64, ga);                                     // ga=Ah0(1) [4]
  issue4(aG + 64 + 128 * K_DIM, gb);                       // gb=Ah1(1) [4]
  asm volatile("s_waitcnt vmcnt(8)" ::: "memory");         // retire B4(tile0)
  asm volatile("s_waitcnt vmcnt(4)" ::: "memory");         // ga done
  cvt_write(ga, smem + 65536, wrO0);                       // Ah0(1)
  issue4(aG + 2 * 64, ga);                                 // ga=Ah0(2) [4]
  stage_half(Bbase + 32768 + 16384, smem, 65536 + 32768 + 16384, tid); // Bh1(1) [2]
  asm volatile("s_waitcnt vmcnt(6)" ::: "memory");         // retire gb (Ah1(1))
  asm volatile("s_waitcnt lgkmcnt(0)" ::: "memory");
  __builtin_amdgcn_s_barrier();

  for (int g = 0; g < NT; ++g) {
    const int bb = g & 1, nbf = bb ^ 1;
    char* ab = smem + bb * 65536;
    const char* B1t = Bbase + (size_t)((g + 1) & ktm) * 32768;
    const char* B2t = Bbase + (size_t)((g + 2) & ktm) * 32768;

    bf16x8 a[4][2], b0[2][2], b1[2][2];

    // ---- P0: reads A(M0)+B(N0); MFMA M0N0; tail: write Ah1(g+1) (no wait) ---
    #pragma unroll
    for (int f = 0; f < 4; ++f)
      #pragma unroll
      for (int s = 0; s < 2; ++s)
        a[f][s] = *(const bf16x8*)(ab + aRow[f] + colw[s]);
    #pragma unroll
    for (int f2 = 0; f2 < 2; ++f2)
      #pragma unroll
      for (int s = 0; s < 2; ++s)
        b0[f2][s] = *(const bf16x8*)(ab + bRow[f2] + colw[s]);
    __builtin_amdgcn_sched_barrier(0);
    __builtin_amdgcn_s_barrier();
    asm volatile("s_waitcnt lgkmcnt(0)" ::: "memory");
    __builtin_amdgcn_sched_barrier(0);
    __builtin_amdgcn_s_setprio(1);
    #pragma unroll
    for (int f = 0; f < 4; ++f)
      #pragma unroll
      for (int f2 = 0; f2 < 2; ++f2)
        #pragma unroll
        for (int s = 0; s < 2; ++s)
          acc[0][f][0][f2] = __builtin_amdgcn_mfma_f32_16x16x32_bf16(
              a[f][s], b0[f2][s], acc[0][f][0][f2], 0, 0, 0);
    __builtin_amdgcn_s_setprio(0);
    cvt_write(gb, smem + nbf * 65536 + 16384, wrO0);       // Ah1(g+1)
    __builtin_amdgcn_sched_barrier(0);
    __builtin_amdgcn_s_barrier();

    // ---- P1: issue gb(Ah1(g+2)); reads B(N1); stage Bh0(g+1); MFMA M0N1 -----
    issue4(aG + (size_t)((g + 2) & ktm) * 64 + 128 * K_DIM, gb);
    #pragma unroll
    for (int f2 = 0; f2 < 2; ++f2)
      #pragma unroll
      for (int s = 0; s < 2; ++s)
        b1[f2][s] = *(const bf16x8*)(ab + bRow[f2] + 16384 + colw[s]);
    stage_half(B1t, smem, nbf * 65536 + 32768, tid);
    __builtin_amdgcn_sched_barrier(0);
    __builtin_amdgcn_s_barrier();
    asm volatile("s_waitcnt lgkmcnt(0)" ::: "memory");
    __builtin_amdgcn_sched_barrier(0);
    __builtin_amdgcn_s_setprio(1);
    #pragma unroll
    for (int f = 0; f < 4; ++f)
      #pragma unroll
      for (int f2 = 0; f2 < 2; ++f2)
        #pragma unroll
        for (int s = 0; s < 2; ++s)
          acc[0][f][1][f2] = __builtin_amdgcn_mfma_f32_16x16x32_bf16(
              a[f][s], b1[f2][s], acc[0][f][1][f2], 0, 0, 0);
    __builtin_amdgcn_s_setprio(0);
    __builtin_amdgcn_sched_barrier(0);
    __builtin_amdgcn_s_barrier();

    // ---- P2: reads A(M1); MFMA M1N1; tail: vmcnt(8) -> write Ah0(g+2) -------
    #pragma unroll
    for (int f = 0; f < 4; ++f)
      #pragma unroll
      for (int s = 0; s < 2; ++s)
        a[f][s] = *(const bf16x8*)(ab + aRow[f] + 16384 + colw[s]);
    __builtin_amdgcn_sched_barrier(0);
    __builtin_amdgcn_s_barrier();
    asm volatile("s_waitcnt lgkmcnt(0)" ::: "memory");
    __builtin_amdgcn_sched_barrier(0);
    __builtin_amdgcn_s_setprio(1);
    #pragma unroll
    for (int f = 0; f < 4; ++f)
      #pragma unroll
      for (int f2 = 0; f2 < 2; ++f2)
        #pragma unroll
        for (int s = 0; s < 2; ++s)
          acc[1][f][1][f2] = __builtin_amdgcn_mfma_f32_16x16x32_bf16(
              a[f][s], b1[f2][s], acc[1][f][1][f2], 0, 0, 0);
    __builtin_amdgcn_s_setprio(0);
    asm volatile("s_waitcnt vmcnt(8)" ::: "memory");       // retire ga (3.5 ph old)
    cvt_write(ga, smem + bb * 65536, wrO0);                // Ah0(g+2)
    __builtin_amdgcn_sched_barrier(0);
    __builtin_amdgcn_s_barrier();

    // ---- P3: issue ga(Ah0(g+3)); stage Bh1(g+2); MFMA M1N0; vmcnt(6) --------
    issue4(aG + (size_t)((g + 3) & ktm) * 64, ga);
    stage_half(B2t + 16384, smem, bb * 65536 + 32768 + 16384, tid);
    __builtin_amdgcn_sched_barrier(0);
    __builtin_amdgcn_s_barrier();
    __builtin_amdgcn_s_setprio(1);
    #pragma unroll
    for (int f = 0; f < 4; ++f)
      #pragma unroll
      for (int f2 = 0; f2 < 2; ++f2)
        #pragma unroll
        for (int s = 0; s < 2; ++s)
          acc[1][f][0][f2] = __builtin_amdgcn_mfma_f32_16x16x32_bf16(
              a[f][s], b0[f2][s], acc[1][f][0][f2], 0, 0, 0);
    __builtin_amdgcn_s_setprio(0);
    asm volatile("s_waitcnt vmcnt(6)" ::: "memory");       // retire Bh1(g+1),gb,Bh0(g+1)
    __builtin_amdgcn_sched_barrier(0);
    __builtin_amdgcn_s_barrier();
  }

  // C-write: frag layout col=lane&15, row=(lane>>4)*4+reg (m89-verified).
  const int lq = lane >> 4;
  #pragma unroll
  for (int qm = 0; qm < 2; ++qm)
    #pragma unroll
    for (int f = 0; f < 4; ++f) {
      const int rowg = mt * 256 + qm * 128 + wm * 64 + f * 16 + lq * 4;
      #pragma unroll
      for (int reg = 0; reg < 4; ++reg) {
        float* Vr = V + (size_t)(rowg + reg) * N_DIM + nt * 256 + wn * 32 + lrow;
        #pragma unroll
        for (int qn = 0; qn < 2; ++qn)
          #pragma unroll
          for (int f2 = 0; f2 < 2; ++f2)
            Vr[qn * 128 + f2 * 16] = acc[qm][f][qn][f2][reg];
      }
    }
}

// ---- Householder epilogue: combines split-K partials, in-place on d_out ------
__global__ __launch_bounds__(256) void householder_ep(
    const float* __restrict__ x, const float* __restrict__ bias,
    float* __restrict__ vio, const float* __restrict__ V2,
    float* __restrict__ logdet) {
  const int row = blockIdx.x;
  const int t = threadIdx.x;
  float4* vr = (float4*)(vio + (size_t)row * N_DIM);
  const float4* xr = (const float4*)(x + (size_t)row * N_DIM);
  const float4* br = (const float4*)bias;

  float4 v = vr[t];
  if (V2) {
    float4 v2 = ((const float4*)(V2 + (size_t)row * N_DIM))[t];
    v.x += v2.x; v.y += v2.y; v.z += v2.z; v.w += v2.w;
  }
  float4 bb = br[t];
  v.x += bb.x; v.y += bb.y; v.z += bb.z; v.w += bb.w;
  float4 xx = xr[t];

  float dot = v.x * xx.x + v.y * xx.y + v.z * xx.z + v.w * xx.w;
  float nsq = v.x * v.x + v.y * v.y + v.z * v.z + v.w * v.w;

  #pragma unroll
  for (int off = 32; off > 0; off >>= 1) {
    dot += __shfl_down(dot, off);
    nsq += __shfl_down(nsq, off);
  }
  __shared__ float sd[4], sn[4];
  if ((t & 63) == 0) { sd[t >> 6] = dot; sn[t >> 6] = nsq; }
  __syncthreads();
  dot = sd[0] + sd[1] + sd[2] + sd[3];
  nsq = sn[0] + sn[1] + sn[2] + sn[3];

  const float f = 2.0f * dot / sqrtf(nsq);
  float4 o;
  o.x = xx.x - f * v.x;
  o.y = xx.y - f * v.y;
  o.z = xx.z - f * v.z;
  o.w = xx.w - f * v.w;
  vr[t] = o;
  if (t == 0) logdet[row] = 0.0f;
}

extern "C" void kernel_launch(void* const* d_in, const int* in_sizes, int n_in,
                              void* d_out, int out_size, void* d_ws, size_t ws_size,
                              hipStream_t stream) {
  const float* x   = (const float*)d_in[0];   // [8192,1024]
  const float* enc = (const float*)d_in[1];   // [8192,4096]
  const float* W   = (const float*)d_in[2];   // [1024,4096]
  const float* b   = (const float*)d_in[3];   // [1024]

  float* out    = (float*)d_out;
  float* v      = out;                              // V partial 0 lives in d_out
  float* logdet = out + (size_t)M_DIM * N_DIM;

  char*  packB = (char*)d_ws;                               // 8 MB
  float* V2    = (float*)(packB + (size_t)8 * 1024 * 1024); // 32 MB

  const size_t need2 = (size_t)40 * 1024 * 1024;
  const int nsplit = (ws_size >= need2) ? 2 : 1;

  pack_w<<<2048, 256, 0, stream>>>(W, (int4*)packB);

  hipFuncSetAttribute((const void*)gemm8, hipFuncAttributeMaxDynamicSharedMemorySize, 131072);
  gemm8<<<dim3(128 * nsplit), 512, 131072, stream>>>(
      enc, packB, v, nsplit == 2 ? V2 : nullptr, 64 / nsplit);

  householder_ep<<<M_DIM, 256, 0, stream>>>(x, b, v, nsplit == 2 ? V2 : nullptr, logdet);
}